// Round 7
// baseline (174.856 us; speedup 1.0000x reference)
//
#include <hip/hip_runtime.h>
#include <math.h>

#define E_TYPES 20
#define NBLK 2
#define NANG 7
#define CS 384
#define CH 128
#define N_TOK (8 * 2048)
#define TOK 32
#define TPB 512                              // 8 waves
#define PREPB 256
#define MAX_TILES (N_TOK / TOK + E_TYPES)    // 532
#define GRID_M 536                           // 8 * 67, swizzle domain
#define PADN 2048                            // per-type perm region (ints)

// ---- workspace: int control region ----
#define CNT_OFF 0            // 20 counts (written by prep block 63)
#define PERM_OFF 64          // 20 x PADN fixed per-type regions
// ---- workspace: fragment-packed split-bf16 weights (byte offsets) ----
#define WT1_OFF (256 * 1024)                 // phase-1 concat [768x128] per e
#define WT1_SZ  (20 * 8 * 24 * 2048)         // e x nt(8) x kb(24) x (hi 1KB + lo 1KB)
#define WTR_OFF (WT1_OFF + WT1_SZ)           // residual: e x m4(4) x nt(8) x kb(4)

typedef __attribute__((ext_vector_type(8))) short bfrag;
typedef __attribute__((ext_vector_type(4))) float f32x4;

__device__ __forceinline__ void split_bf16(float x, unsigned short& h, unsigned short& l) {
    unsigned int u = __float_as_uint(x);
    unsigned int hb = (u + 0x7FFFu + ((u >> 16) & 1u)) & 0xFFFF0000u;
    h = (unsigned short)(hb >> 16);
    float r = x - __uint_as_float(hb);
    unsigned int v = __float_as_uint(r);
    l = (unsigned short)((v + 0x7FFFu + ((v >> 16) & 1u)) >> 16);
}

// ============ prep: fused scatter (blocks 0..63) + weight transpose ============
// (unchanged from round 6 — output layout bit-validated by rounds 5/6 passes)
__global__ __launch_bounds__(PREPB)
void prep_k(const float* __restrict__ Win, const float* __restrict__ Winit,
            const float* __restrict__ Wb1, const float* __restrict__ Wb2,
            const int* __restrict__ aatype, int* __restrict__ wsI,
            unsigned short* __restrict__ wt)
{
    __shared__ unsigned short tp[4][2][32][134];
    __shared__ int lh[E_TYPES], lcur[E_TYPES];
    int bid = blockIdx.x, t = threadIdx.x;

    if (bid < 64) {   // deterministic scatter, no global atomics
        if (t < E_TYPES) { lh[t] = 0; lcur[t] = 0; }
        __syncthreads();
        for (int i = t; i < bid * 256; i += 256) atomicAdd(&lh[aatype[i]], 1);
        __syncthreads();
        int idx = bid * 256 + t;
        int e = aatype[idx];
        int r = lh[e] + atomicAdd(&lcur[e], 1);
        if (r < PADN) wsI[PERM_OFF + e * PADN + r] = idx;
        if (bid == 63) {
            __syncthreads();
            if (t < E_TYPES) wsI[CNT_OFF + t] = lh[t] + lcur[t];
        }
        return;
    }

    int w = t >> 6, lane = t & 63, lane15 = lane & 15, quad = lane >> 4;
    int wid = (bid - 64) * 4 + w;      // 0..799 tiles
    const float* srcbase;
    int phase1, e, kt, m4 = 0;
    if (wid < 480) {
        phase1 = 1;
        e = wid / 24; kt = wid % 24;
        srcbase = (kt < 12) ? Win   + ((size_t)e * CS + kt * 32) * CH
                            : Winit + ((size_t)e * CS + (kt - 12) * 32) * CH;
    } else {
        phase1 = 0;
        int rid = wid - 480;
        e = rid >> 4; m4 = (rid >> 2) & 3; kt = rid & 3;
        const float* W = (m4 & 1) ? Wb2 : Wb1;
        srcbase = W + (((size_t)e * NBLK + (m4 >> 1)) * CH + kt * 32) * CH;
    }

    #pragma unroll 4
    for (int i = 0; i < 16; i++) {
        int idx = i * 64 + lane;
        int row = idx >> 5, c4 = idx & 31;
        float4 v = *(const float4*)(srcbase + (size_t)row * CH + c4 * 4);
        ushort4 hv, lv;
        split_bf16(v.x, hv.x, lv.x);
        split_bf16(v.y, hv.y, lv.y);
        split_bf16(v.z, hv.z, lv.z);
        split_bf16(v.w, hv.w, lv.w);
        *(ushort4*)&tp[w][0][row][c4 * 4] = hv;
        *(ushort4*)&tp[w][1][row][c4 * 4] = lv;
    }
    #pragma unroll
    for (int nt = 0; nt < 8; nt++) {
        bfrag hb, lb;
        #pragma unroll
        for (int j = 0; j < 8; j++) {
            hb[j] = (short)tp[w][0][quad * 8 + j][nt * 16 + lane15];
            lb[j] = (short)tp[w][1][quad * 8 + j][nt * 16 + lane15];
        }
        size_t blk = phase1 ? (size_t)((e * 8 + nt) * 24 + kt)
                            : (size_t)((((e * 4 + m4) * 8) + nt) * 4 + kt);
        unsigned short* dst = wt + (phase1 ? WT1_OFF / 2 : WTR_OFF / 2)
                              + blk * 1024 + lane * 8;
        *(bfrag*)dst = hb;
        *(bfrag*)(dst + 512) = lb;
    }
}

#define MFMA(a, b, c) __builtin_amdgcn_mfma_f32_16x16x32_bf16((a), (b), (c), 0, 0, 0)

// 8 waves: wave w handles m-tile (w>>2) x n-cols [32*(w&3), 32*(w&3)+32).
// A-fragments fragment-major in LDS (conflict-free b128); epilogue aliases
// the same LDS (Afrag dead by then).
__global__ __launch_bounds__(TPB)
void angle_main(const float* __restrict__ s, const float* __restrict__ si,
                const float* __restrict__ b_in, const float* __restrict__ b_init2,
                const float* __restrict__ bb1, const float* __restrict__ bb2,
                const float* __restrict__ Wout, const float* __restrict__ b_out,
                const int* __restrict__ wsI, const unsigned short* __restrict__ wt,
                float* __restrict__ out)
{
    __shared__ __align__(16) unsigned char smem_raw[32768];
    typedef unsigned short AfragT[2][2][512][8];   // [buf][hi/lo][fi][8]
    AfragT& Afrag = *reinterpret_cast<AfragT*>(smem_raw);
    float (*Hf)[130] = reinterpret_cast<float(*)[130]>(smem_raw);          // 16640 B
    float (*Of)[16]  = reinterpret_cast<float(*)[16]>(smem_raw + 16640);   // +2048 B
    __shared__ int ptok[TOK];
    __shared__ int poffs[E_TYPES + 1];

    int t = threadIdx.x;
    if (t == 0) {
        int off = 0;
        for (int e = 0; e < E_TYPES; e++) {
            poffs[e] = off;
            off += (wsI[CNT_OFF + e] + TOK - 1) & ~(TOK - 1);
        }
        poffs[E_TYPES] = off;
    }
    __syncthreads();

    // XCD swizzle: consecutive blockIdx round-robin XCDs; give each XCD a
    // contiguous tile range -> contiguous expert range -> weights fit its L2.
    int bid = blockIdx.x;
    int tile = (bid & 7) * (GRID_M / 8) + (bid >> 3);
    int pos = tile * TOK;
    if (pos >= poffs[E_TYPES]) return;
    int e = 0;
    while (e < E_TYPES - 1 && pos >= poffs[e + 1]) e++;
    int n = wsI[CNT_OFF + e] - (pos - poffs[e]);
    if (n > TOK) n = TOK;
    if (t < TOK)
        ptok[t] = wsI[PERM_OFF + e * PADN + (pos - poffs[e]) + ((t < n) ? t : 0)];

    int w = t >> 6, lane = t & 63, lane15 = lane & 15, quad = lane >> 4;
    int mw = w >> 2;               // m-tile 0/1 (token rows mw*16..mw*16+15)
    int np = w & 3;                // n-tile pair (cols 32*np..32*np+31)
    int nc0 = (2 * np) * 16 + lane15, nc1 = nc0 + 16;

    __syncthreads();

    const bfrag* wt1 = (const bfrag*)((const char*)wt + WT1_OFF);
    const bfrag* wtr = (const bfrag*)((const char*)wt + WTR_OFF);

    f32x4 acc[2];   // [n-tile]; C: col=lane15, row=quad*4+reg (verified r5/r6)
    {
        float bv0 = b_in[e * CH + nc0] + b_init2[e * CH + nc0];
        float bv1 = b_in[e * CH + nc1] + b_init2[e * CH + nc1];
        acc[0] = (f32x4){bv0, bv0, bv0, bv0};
        acc[1] = (f32x4){bv1, bv1, bv1, bv1};
    }

    // staging: thread t loads token row t>>4, col-16 group t&15 (2 float4s)
    int stok = t >> 4, sc = t & 15;
    const float* rowp_s  = s  + (size_t)ptok[stok] * CS;
    const float* rowp_si = si + (size_t)ptok[stok] * CS;

    float4 pf[2][2];
    #pragma unroll
    for (int q = 0; q < 2; q++)
        pf[0][q] = *(const float4*)(rowp_s + sc * 4 + 64 * q);

    // ---- phase 1: h = [relu(s) relu(si)] @ [Win;Winit] + biases, K=768 ----
    #pragma unroll
    for (int c = 0; c < 6; c++) {
        int buf = c & 1;
        __syncthreads();
        #pragma unroll
        for (int q = 0; q < 2; q++) {
            float4 v = pf[buf][q];
            ushort4 hv, lv;
            split_bf16(fmaxf(v.x, 0.f), hv.x, lv.x);
            split_bf16(fmaxf(v.y, 0.f), hv.y, lv.y);
            split_bf16(fmaxf(v.z, 0.f), hv.z, lv.z);
            split_bf16(fmaxf(v.w, 0.f), hv.w, lv.w);
            int fi = ((sc >> 1) + 8 * q) * 32 + stok;
            *(ushort4*)&Afrag[buf][0][fi][(sc & 1) * 4] = hv;
            *(ushort4*)&Afrag[buf][1][fi][(sc & 1) * 4] = lv;
        }
        if (c + 1 < 6) {
            const float* rp = ((c + 1) < 3 ? rowp_s : rowp_si) + ((c + 1) % 3) * 128;
            #pragma unroll
            for (int q = 0; q < 2; q++)
                pf[(c + 1) & 1][q] = *(const float4*)(rp + sc * 4 + 64 * q);
        }
        __syncthreads();
        #pragma unroll
        for (int ks = 0; ks < 4; ks++) {
            int kb = c * 4 + ks;
            int fib = (ks * 4 + quad) * 32 + mw * 16;
            bfrag ah = *(const bfrag*)&Afrag[buf][0][fib + lane15][0];
            bfrag al = *(const bfrag*)&Afrag[buf][1][fib + lane15][0];
            size_t b0 = ((size_t)(e * 8 + 2 * np) * 24 + kb) * 128;
            size_t b1 = ((size_t)(e * 8 + 2 * np + 1) * 24 + kb) * 128;
            bfrag bh0 = wt1[b0 + lane], bl0 = wt1[b0 + 64 + lane];
            bfrag bh1 = wt1[b1 + lane], bl1 = wt1[b1 + 64 + lane];
            acc[0] = MFMA(ah, bh0, acc[0]);
            acc[0] = MFMA(ah, bl0, acc[0]);
            acc[0] = MFMA(al, bh0, acc[0]);
            acc[1] = MFMA(ah, bh1, acc[1]);
            acc[1] = MFMA(ah, bl1, acc[1]);
            acc[1] = MFMA(al, bh1, acc[1]);
        }
    }

    // ---- 2 residual blocks (A-frags in buf 0) ----
    f32x4 a2[2];
    #pragma unroll
    for (int b = 0; b < NBLK; b++) {
        #pragma unroll
        for (int stage = 0; stage < 2; stage++) {
            int g = 2 * b + stage;
            __syncthreads();
            #pragma unroll
            for (int nl = 0; nl < 2; nl++) {
                f32x4 v = (stage == 0) ? acc[nl] : a2[nl];
                int nn = (2 * np + nl) * 16 + lane15;
                int fib = ((nn >> 5) * 4 + ((nn >> 3) & 3)) * 32;
                int j = nn & 7;
                #pragma unroll
                for (int r = 0; r < 4; r++) {
                    int m = mw * 16 + quad * 4 + r;
                    unsigned short hh, ll;
                    split_bf16(fmaxf(v[r], 0.f), hh, ll);
                    Afrag[0][0][fib + m][j] = hh;
                    Afrag[0][1][fib + m][j] = ll;
                }
            }
            __syncthreads();

            const float* bias = (stage == 0) ? bb1 : bb2;
            f32x4 an[2];
            {
                float bv0 = bias[(e * NBLK + b) * CH + nc0];
                float bv1 = bias[(e * NBLK + b) * CH + nc1];
                an[0] = (f32x4){bv0, bv0, bv0, bv0};
                an[1] = (f32x4){bv1, bv1, bv1, bv1};
            }
            #pragma unroll
            for (int ks = 0; ks < 4; ks++) {
                int fib = (ks * 4 + quad) * 32 + mw * 16;
                bfrag ah = *(const bfrag*)&Afrag[0][0][fib + lane15][0];
                bfrag al = *(const bfrag*)&Afrag[0][1][fib + lane15][0];
                size_t b0 = ((size_t)((e * 4 + g) * 8 + 2 * np) * 4 + ks) * 128;
                size_t b1 = ((size_t)((e * 4 + g) * 8 + 2 * np + 1) * 4 + ks) * 128;
                bfrag bh0 = wtr[b0 + lane], bl0 = wtr[b0 + 64 + lane];
                bfrag bh1 = wtr[b1 + lane], bl1 = wtr[b1 + 64 + lane];
                an[0] = MFMA(ah, bh0, an[0]);
                an[0] = MFMA(ah, bl0, an[0]);
                an[0] = MFMA(al, bh0, an[0]);
                an[1] = MFMA(ah, bh1, an[1]);
                an[1] = MFMA(ah, bl1, an[1]);
                an[1] = MFMA(al, bh1, an[1]);
            }
            if (stage == 0) {
                a2[0] = an[0]; a2[1] = an[1];
            } else {
                acc[0] += an[0]; acc[1] += an[1];
            }
        }
    }

    // ---- epilogue: relu(h) fp32 -> LDS (aliases dead Afrag memory) ----
    __syncthreads();
    #pragma unroll
    for (int nl = 0; nl < 2; nl++) {
        f32x4 v = acc[nl];
        int nn = (2 * np + nl) * 16 + lane15;
        #pragma unroll
        for (int r = 0; r < 4; r++)
            Hf[mw * 16 + quad * 4 + r][nn] = fmaxf(v[r], 0.f);
    }
    __syncthreads();

    // ---- out = relu(h) @ Wout + b_out (128 -> 14) ----
    const float* WoutE = Wout + (size_t)e * CH * (NANG * 2);
    const float* boutE = b_out + (size_t)e * (NANG * 2);
    for (int idx = t; idx < n * (NANG * 2); idx += TPB) {
        int i = idx / (NANG * 2);
        int o = idx % (NANG * 2);
        float v = boutE[o];
        #pragma unroll 4
        for (int k = 0; k < CH; k++)
            v = fmaf(Hf[i][k], WoutE[(size_t)k * (NANG * 2) + o], v);
        Of[i][o] = v;
    }
    __syncthreads();

    // ---- pair-normalize and store ----
    for (int idx = t; idx < n * NANG; idx += TPB) {
        int i = idx / NANG;
        int a = idx % NANG;
        float x = Of[i][2 * a];
        float y = Of[i][2 * a + 1];
        float nr = fmaxf(sqrtf(x * x + y * y), 1e-12f);
        size_t base = (size_t)ptok[i] * (NANG * 2) + 2 * a;
        out[base]     = x / nr;
        out[base + 1] = y / nr;
    }
}

extern "C" void kernel_launch(void* const* d_in, const int* in_sizes, int n_in,
                              void* d_out, int out_size, void* d_ws, size_t ws_size,
                              hipStream_t stream) {
    const float* s       = (const float*)d_in[0];
    const float* s_init  = (const float*)d_in[1];
    const int*   aatype  = (const int*)d_in[2];
    const float* Win     = (const float*)d_in[3];
    const float* b_in    = (const float*)d_in[4];
    const float* Winit   = (const float*)d_in[5];
    const float* b_init2 = (const float*)d_in[6];
    const float* Wb1     = (const float*)d_in[7];
    const float* bb1     = (const float*)d_in[8];
    const float* Wb2     = (const float*)d_in[9];
    const float* bb2     = (const float*)d_in[10];
    const float* Wout    = (const float*)d_in[11];
    const float* b_out   = (const float*)d_in[12];
    int* wsI = (int*)d_ws;
    unsigned short* wt = (unsigned short*)d_ws;
    float* out = (float*)d_out;

    hipLaunchKernelGGL(prep_k, dim3(64 + 200), dim3(PREPB), 0, stream,
                       Win, Winit, Wb1, Wb2, aatype, wsI, wt);
    hipLaunchKernelGGL(angle_main, dim3(GRID_M), dim3(TPB), 0, stream,
                       s, s_init, b_in, b_init2, bb1, bb2, Wout, b_out,
                       wsI, wt, out);
}

// Round 8
// 168.182 us; speedup vs baseline: 1.0397x; 1.0397x over previous
//
#include <hip/hip_runtime.h>
#include <math.h>

#define E_TYPES 20
#define NBLK 2
#define NANG 7
#define CS 384
#define CH 128
#define N_TOK (8 * 2048)
#define TOK 32
#define TPB 256                              // 4 waves
#define PREPB 256
#define GRID_M 536                           // 8 * 67 swizzle domain (>= 532 tiles)
#define PADN 2048                            // per-type perm region (ints)

// ---- workspace: int control region ----
#define CNT_OFF 0            // 20 counts (written by prep block 63)
#define PERM_OFF 64          // 20 x PADN fixed per-type regions
// ---- workspace: fragment-packed split-bf16 weights (byte offsets) ----
#define WT1_OFF (256 * 1024)                 // phase-1 concat [768x128] per e
#define WT1_SZ  (20 * 8 * 24 * 2048)         // e x nt(8) x kb(24) x (hi 1KB + lo 1KB)
#define WTR_OFF (WT1_OFF + WT1_SZ)           // residual: e x m4(4) x nt(8) x kb(4)

typedef __attribute__((ext_vector_type(8))) short bfrag;
typedef __attribute__((ext_vector_type(4))) float f32x4;

__device__ __forceinline__ void split_bf16(float x, unsigned short& h, unsigned short& l) {
    unsigned int u = __float_as_uint(x);
    unsigned int hb = (u + 0x7FFFu + ((u >> 16) & 1u)) & 0xFFFF0000u;
    h = (unsigned short)(hb >> 16);
    float r = x - __uint_as_float(hb);
    unsigned int v = __float_as_uint(r);
    l = (unsigned short)((v + 0x7FFFu + ((v >> 16) & 1u)) >> 16);
}

// ============ prep: fused scatter (blocks 0..63) + weight transpose ============
// (bit-validated by rounds 5-7 passes — unchanged)
__global__ __launch_bounds__(PREPB)
void prep_k(const float* __restrict__ Win, const float* __restrict__ Winit,
            const float* __restrict__ Wb1, const float* __restrict__ Wb2,
            const int* __restrict__ aatype, int* __restrict__ wsI,
            unsigned short* __restrict__ wt)
{
    __shared__ unsigned short tp[4][2][32][134];
    __shared__ int lh[E_TYPES], lcur[E_TYPES];
    int bid = blockIdx.x, t = threadIdx.x;

    if (bid < 64) {
        if (t < E_TYPES) { lh[t] = 0; lcur[t] = 0; }
        __syncthreads();
        for (int i = t; i < bid * 256; i += 256) atomicAdd(&lh[aatype[i]], 1);
        __syncthreads();
        int idx = bid * 256 + t;
        int e = aatype[idx];
        int r = lh[e] + atomicAdd(&lcur[e], 1);
        if (r < PADN) wsI[PERM_OFF + e * PADN + r] = idx;
        if (bid == 63) {
            __syncthreads();
            if (t < E_TYPES) wsI[CNT_OFF + t] = lh[t] + lcur[t];
        }
        return;
    }

    int w = t >> 6, lane = t & 63, lane15 = lane & 15, quad = lane >> 4;
    int wid = (bid - 64) * 4 + w;
    const float* srcbase;
    int phase1, e, kt, m4 = 0;
    if (wid < 480) {
        phase1 = 1;
        e = wid / 24; kt = wid % 24;
        srcbase = (kt < 12) ? Win   + ((size_t)e * CS + kt * 32) * CH
                            : Winit + ((size_t)e * CS + (kt - 12) * 32) * CH;
    } else {
        phase1 = 0;
        int rid = wid - 480;
        e = rid >> 4; m4 = (rid >> 2) & 3; kt = rid & 3;
        const float* W = (m4 & 1) ? Wb2 : Wb1;
        srcbase = W + (((size_t)e * NBLK + (m4 >> 1)) * CH + kt * 32) * CH;
    }

    #pragma unroll 4
    for (int i = 0; i < 16; i++) {
        int idx = i * 64 + lane;
        int row = idx >> 5, c4 = idx & 31;
        float4 v = *(const float4*)(srcbase + (size_t)row * CH + c4 * 4);
        ushort4 hv, lv;
        split_bf16(v.x, hv.x, lv.x);
        split_bf16(v.y, hv.y, lv.y);
        split_bf16(v.z, hv.z, lv.z);
        split_bf16(v.w, hv.w, lv.w);
        *(ushort4*)&tp[w][0][row][c4 * 4] = hv;
        *(ushort4*)&tp[w][1][row][c4 * 4] = lv;
    }
    #pragma unroll
    for (int nt = 0; nt < 8; nt++) {
        bfrag hb, lb;
        #pragma unroll
        for (int j = 0; j < 8; j++) {
            hb[j] = (short)tp[w][0][quad * 8 + j][nt * 16 + lane15];
            lb[j] = (short)tp[w][1][quad * 8 + j][nt * 16 + lane15];
        }
        size_t blk = phase1 ? (size_t)((e * 8 + nt) * 24 + kt)
                            : (size_t)((((e * 4 + m4) * 8) + nt) * 4 + kt);
        unsigned short* dst = wt + (phase1 ? WT1_OFF / 2 : WTR_OFF / 2)
                              + blk * 1024 + lane * 8;
        *(bfrag*)dst = hb;
        *(bfrag*)(dst + 512) = lb;
    }
}

#define MFMA(a, b, c) __builtin_amdgcn_mfma_f32_16x16x32_bf16((a), (b), (c), 0, 0, 0)

// 12 MFMAs of one k-step, 2 m-tiles x 2 n-tiles, 3-term split (validated r5/r6)
#define KSTEP(AH0, AL0, AH1, AL1, B, ACC)                    \
    ACC[0][0] = MFMA(AH0, B[0], ACC[0][0]);                  \
    ACC[0][0] = MFMA(AH0, B[1], ACC[0][0]);                  \
    ACC[0][0] = MFMA(AL0, B[0], ACC[0][0]);                  \
    ACC[0][1] = MFMA(AH0, B[2], ACC[0][1]);                  \
    ACC[0][1] = MFMA(AH0, B[3], ACC[0][1]);                  \
    ACC[0][1] = MFMA(AL0, B[2], ACC[0][1]);                  \
    ACC[1][0] = MFMA(AH1, B[0], ACC[1][0]);                  \
    ACC[1][0] = MFMA(AH1, B[1], ACC[1][0]);                  \
    ACC[1][0] = MFMA(AL1, B[0], ACC[1][0]);                  \
    ACC[1][1] = MFMA(AH1, B[2], ACC[1][1]);                  \
    ACC[1][1] = MFMA(AH1, B[3], ACC[1][1]);                  \
    ACC[1][1] = MFMA(AL1, B[2], ACC[1][1]);

__global__ __launch_bounds__(TPB)
void angle_main(const float* __restrict__ s, const float* __restrict__ si,
                const float* __restrict__ b_in, const float* __restrict__ b_init2,
                const float* __restrict__ bb1, const float* __restrict__ bb2,
                const float* __restrict__ Wout, const float* __restrict__ b_out,
                const int* __restrict__ wsI, const unsigned short* __restrict__ wt,
                float* __restrict__ out)
{
    __shared__ __align__(16) unsigned char smem_raw[32768];
    typedef unsigned short AfragT[2][2][512][8];   // [buf][hi/lo][fi][8]
    AfragT& Afrag = *reinterpret_cast<AfragT*>(smem_raw);
    float (*Hf)[132] = reinterpret_cast<float(*)[132]>(smem_raw);          // 16896 B
    float (*Of)[16]  = reinterpret_cast<float(*)[16]>(smem_raw + 16896);   // +2048 B
    __shared__ int ptok[TOK];
    __shared__ int poffs[E_TYPES + 1];

    int t = threadIdx.x;
    // parallel padded-prefix (was serial 20-step L2 scan on thread 0)
    if (t <= E_TYPES) {
        int off = 0;
        for (int e = 0; e < t; e++)
            off += (wsI[CNT_OFF + e] + TOK - 1) & ~(TOK - 1);
        poffs[t] = off;
    }
    __syncthreads();

    // XCD swizzle (validated r7: FETCH 77->33MB): contiguous tile range per XCD
    int bid = blockIdx.x;
    int tile = (bid & 7) * (GRID_M / 8) + (bid >> 3);
    int pos = tile * TOK;
    if (pos >= poffs[E_TYPES]) return;
    int e = 0;
    while (e < E_TYPES - 1 && pos >= poffs[e + 1]) e++;
    int n = wsI[CNT_OFF + e] - (pos - poffs[e]);
    if (n > TOK) n = TOK;
    if (t < TOK)
        ptok[t] = wsI[PERM_OFF + e * PADN + (pos - poffs[e]) + ((t < n) ? t : 0)];

    int w = t >> 6, lane = t & 63, lane15 = lane & 15, quad = lane >> 4;
    int nc0 = (2 * w) * 16 + lane15, nc1 = nc0 + 16;

    __syncthreads();

    const bfrag* wt1 = (const bfrag*)((const char*)wt + WT1_OFF);
    const bfrag* wtr = (const bfrag*)((const char*)wt + WTR_OFF);

    f32x4 acc[2][2];   // [m-tile][n-tile]; C: col=lane15, row=quad*4+reg
    {
        float bv0 = b_in[e * CH + nc0] + b_init2[e * CH + nc0];
        float bv1 = b_in[e * CH + nc1] + b_init2[e * CH + nc1];
        #pragma unroll
        for (int mt = 0; mt < 2; mt++) {
            acc[mt][0] = (f32x4){bv0, bv0, bv0, bv0};
            acc[mt][1] = (f32x4){bv1, bv1, bv1, bv1};
        }
    }

    // staging ids: thread t loads token row t>>3, col group t&7 (4 float4s)
    int stok = t >> 3, sc = t & 7;
    const float* rowp_s  = s  + (size_t)ptok[stok] * CS;
    const float* rowp_si = si + (size_t)ptok[stok] * CS;

    float4 pf[2][4];
    #pragma unroll
    for (int q = 0; q < 4; q++)
        pf[0][q] = *(const float4*)(rowp_s + sc * 4 + 32 * q);

    bfrag Bc[4], Bn[4];   // B double-buffer: {bh0, bl0, bh1, bl1}

    // ---- phase 1: h = [relu(s) relu(si)] @ [Win;Winit] + biases, K=768 ----
    #pragma unroll
    for (int c = 0; c < 6; c++) {
        int buf = c & 1;
        __syncthreads();   // buf's previous readers (chunk c-2) done
        #pragma unroll
        for (int q = 0; q < 4; q++) {
            float4 v = pf[buf][q];
            ushort4 hv, lv;
            split_bf16(fmaxf(v.x, 0.f), hv.x, lv.x);
            split_bf16(fmaxf(v.y, 0.f), hv.y, lv.y);
            split_bf16(fmaxf(v.z, 0.f), hv.z, lv.z);
            split_bf16(fmaxf(v.w, 0.f), hv.w, lv.w);
            int fi = (q * 4 + (sc >> 1)) * 32 + stok;
            *(ushort4*)&Afrag[buf][0][fi][(sc & 1) * 4] = hv;
            *(ushort4*)&Afrag[buf][1][fi][(sc & 1) * 4] = lv;
        }
        __syncthreads();   // buf ready
        // A-prefetch for chunk c+1 issued now: lands during this chunk's MFMAs
        if (c + 1 < 6) {
            const float* rp = ((c + 1) < 3 ? rowp_s : rowp_si) + ((c + 1) % 3) * 128;
            #pragma unroll
            for (int q = 0; q < 4; q++)
                pf[(c + 1) & 1][q] = *(const float4*)(rp + sc * 4 + 32 * q);
        }
        // B pipeline: preload ks=0; prefetch ks+1 during MFMA of ks
        {
            size_t b0 = ((size_t)(e * 8 + 2 * w) * 24 + c * 4) * 128;
            size_t b1 = ((size_t)(e * 8 + 2 * w + 1) * 24 + c * 4) * 128;
            Bc[0] = wt1[b0 + lane]; Bc[1] = wt1[b0 + 64 + lane];
            Bc[2] = wt1[b1 + lane]; Bc[3] = wt1[b1 + 64 + lane];
        }
        #pragma unroll
        for (int ks = 0; ks < 4; ks++) {
            if (ks < 3) {
                int kb = c * 4 + ks + 1;
                size_t b0 = ((size_t)(e * 8 + 2 * w) * 24 + kb) * 128;
                size_t b1 = ((size_t)(e * 8 + 2 * w + 1) * 24 + kb) * 128;
                Bn[0] = wt1[b0 + lane]; Bn[1] = wt1[b0 + 64 + lane];
                Bn[2] = wt1[b1 + lane]; Bn[3] = wt1[b1 + 64 + lane];
            }
            int fib = (ks * 4 + quad) * 32;
            bfrag ah0 = *(const bfrag*)&Afrag[buf][0][fib + lane15][0];
            bfrag ah1 = *(const bfrag*)&Afrag[buf][0][fib + 16 + lane15][0];
            bfrag al0 = *(const bfrag*)&Afrag[buf][1][fib + lane15][0];
            bfrag al1 = *(const bfrag*)&Afrag[buf][1][fib + 16 + lane15][0];
            KSTEP(ah0, al0, ah1, al1, Bc, acc)
            #pragma unroll
            for (int z = 0; z < 4; z++) Bc[z] = Bn[z];
        }
    }

    // ---- 2 residual blocks (A-frags in buf 0) ----
    f32x4 a2[2][2];
    #pragma unroll
    for (int b = 0; b < NBLK; b++) {
        #pragma unroll
        for (int stage = 0; stage < 2; stage++) {
            int g = 2 * b + stage;
            __syncthreads();
            #pragma unroll
            for (int mt = 0; mt < 2; mt++)
                #pragma unroll
                for (int nl = 0; nl < 2; nl++) {
                    f32x4 v = (stage == 0) ? acc[mt][nl] : a2[mt][nl];
                    int nn = (2 * w + nl) * 16 + lane15;
                    int fib = ((nn >> 5) * 4 + ((nn >> 3) & 3)) * 32;
                    int j = nn & 7;
                    #pragma unroll
                    for (int r = 0; r < 4; r++) {
                        int m = mt * 16 + quad * 4 + r;
                        unsigned short hh, ll;
                        split_bf16(fmaxf(v[r], 0.f), hh, ll);
                        Afrag[0][0][fib + m][j] = hh;
                        Afrag[0][1][fib + m][j] = ll;
                    }
                }
            __syncthreads();

            const float* bias = (stage == 0) ? bb1 : bb2;
            f32x4 an[2][2];
            {
                float bv0 = bias[(e * NBLK + b) * CH + nc0];
                float bv1 = bias[(e * NBLK + b) * CH + nc1];
                #pragma unroll
                for (int mt = 0; mt < 2; mt++) {
                    an[mt][0] = (f32x4){bv0, bv0, bv0, bv0};
                    an[mt][1] = (f32x4){bv1, bv1, bv1, bv1};
                }
            }
            {
                size_t b0 = ((size_t)((e * 4 + g) * 8 + 2 * w) * 4) * 128;
                size_t b1 = ((size_t)((e * 4 + g) * 8 + 2 * w + 1) * 4) * 128;
                Bc[0] = wtr[b0 + lane]; Bc[1] = wtr[b0 + 64 + lane];
                Bc[2] = wtr[b1 + lane]; Bc[3] = wtr[b1 + 64 + lane];
            }
            #pragma unroll
            for (int ks = 0; ks < 4; ks++) {
                if (ks < 3) {
                    size_t b0 = ((size_t)((e * 4 + g) * 8 + 2 * w) * 4 + ks + 1) * 128;
                    size_t b1 = ((size_t)((e * 4 + g) * 8 + 2 * w + 1) * 4 + ks + 1) * 128;
                    Bn[0] = wtr[b0 + lane]; Bn[1] = wtr[b0 + 64 + lane];
                    Bn[2] = wtr[b1 + lane]; Bn[3] = wtr[b1 + 64 + lane];
                }
                int fib = (ks * 4 + quad) * 32;
                bfrag ah0 = *(const bfrag*)&Afrag[0][0][fib + lane15][0];
                bfrag ah1 = *(const bfrag*)&Afrag[0][0][fib + 16 + lane15][0];
                bfrag al0 = *(const bfrag*)&Afrag[0][1][fib + lane15][0];
                bfrag al1 = *(const bfrag*)&Afrag[0][1][fib + 16 + lane15][0];
                KSTEP(ah0, al0, ah1, al1, Bc, an)
                #pragma unroll
                for (int z = 0; z < 4; z++) Bc[z] = Bn[z];
            }
            if (stage == 0) {
                #pragma unroll
                for (int mt = 0; mt < 2; mt++)
                    #pragma unroll
                    for (int nl = 0; nl < 2; nl++) a2[mt][nl] = an[mt][nl];
            } else {
                #pragma unroll
                for (int mt = 0; mt < 2; mt++)
                    #pragma unroll
                    for (int nl = 0; nl < 2; nl++) acc[mt][nl] += an[mt][nl];
            }
        }
    }

    // ---- epilogue: relu(h) fp32 -> LDS (aliases dead Afrag memory) ----
    __syncthreads();
    #pragma unroll
    for (int mt = 0; mt < 2; mt++)
        #pragma unroll
        for (int nl = 0; nl < 2; nl++) {
            f32x4 v = acc[mt][nl];
            int nn = (2 * w + nl) * 16 + lane15;
            #pragma unroll
            for (int r = 0; r < 4; r++)
                Hf[mt * 16 + quad * 4 + r][nn] = fmaxf(v[r], 0.f);
        }
    __syncthreads();

    // ---- out = relu(h) @ Wout + b_out (128 -> 14) ----
    const float* WoutE = Wout + (size_t)e * CH * (NANG * 2);
    const float* boutE = b_out + (size_t)e * (NANG * 2);
    for (int idx = t; idx < n * (NANG * 2); idx += TPB) {
        int i = idx / (NANG * 2);
        int o = idx % (NANG * 2);
        float v = boutE[o];
        #pragma unroll 4
        for (int k = 0; k < CH; k++)
            v = fmaf(Hf[i][k], WoutE[(size_t)k * (NANG * 2) + o], v);
        Of[i][o] = v;
    }
    __syncthreads();

    // ---- pair-normalize and store ----
    for (int idx = t; idx < n * NANG; idx += TPB) {
        int i = idx / NANG;
        int a = idx % NANG;
        float x = Of[i][2 * a];
        float y = Of[i][2 * a + 1];
        float nr = fmaxf(sqrtf(x * x + y * y), 1e-12f);
        size_t base = (size_t)ptok[i] * (NANG * 2) + 2 * a;
        out[base]     = x / nr;
        out[base + 1] = y / nr;
    }
}

extern "C" void kernel_launch(void* const* d_in, const int* in_sizes, int n_in,
                              void* d_out, int out_size, void* d_ws, size_t ws_size,
                              hipStream_t stream) {
    const float* s       = (const float*)d_in[0];
    const float* s_init  = (const float*)d_in[1];
    const int*   aatype  = (const int*)d_in[2];
    const float* Win     = (const float*)d_in[3];
    const float* b_in    = (const float*)d_in[4];
    const float* Winit   = (const float*)d_in[5];
    const float* b_init2 = (const float*)d_in[6];
    const float* Wb1     = (const float*)d_in[7];
    const float* bb1     = (const float*)d_in[8];
    const float* Wb2     = (const float*)d_in[9];
    const float* bb2     = (const float*)d_in[10];
    const float* Wout    = (const float*)d_in[11];
    const float* b_out   = (const float*)d_in[12];
    int* wsI = (int*)d_ws;
    unsigned short* wt = (unsigned short*)d_ws;
    float* out = (float*)d_out;

    hipLaunchKernelGGL(prep_k, dim3(64 + 200), dim3(PREPB), 0, stream,
                       Win, Winit, Wb1, Wb2, aatype, wsI, wt);
    hipLaunchKernelGGL(angle_main, dim3(GRID_M), dim3(TPB), 0, stream,
                       s, s_init, b_in, b_init2, bb1, bb2, Wout, b_out,
                       wsI, wt, out);
}